// Round 5
// baseline (270.834 us; speedup 1.0000x reference)
//
#include <hip/hip_runtime.h>
#include <hip/hip_fp16.h>
#include <math.h>

#define C_DIM 128
#define DEG 64
#define NEG_SLOPE 0.2f

typedef float nfloat4 __attribute__((ext_vector_type(4)));

// ---------------------------------------------------------------------------
// Streaming pre-pass: sum = (half)(nf + mem), fp16.
// Exact-size launch: each thread converts 16 elements (64 B per input stream)
// with 8 independent nontemporal 16B loads + 2 stores -> max loads in flight,
// no grid-stride loop. Block 0 also computes combo[] (W_max @ W_score fold).
// ---------------------------------------------------------------------------
__global__ __launch_bounds__(256)
void fuse_sum_half_kernel(const nfloat4* __restrict__ nf4,
                          const nfloat4* __restrict__ mem4,
                          nfloat4* __restrict__ sumh4, long n16,
                          const float* __restrict__ W_max,
                          const float* __restrict__ b_max,
                          const float* __restrict__ W_score,
                          const float* __restrict__ b_score,
                          float* __restrict__ combo) {
    const long idx = (long)blockIdx.x * 256 + threadIdx.x;
    if (idx < n16) {
        const long b = idx * 4;
        nfloat4 a0 = __builtin_nontemporal_load(nf4 + b);
        nfloat4 a1 = __builtin_nontemporal_load(nf4 + b + 1);
        nfloat4 a2 = __builtin_nontemporal_load(nf4 + b + 2);
        nfloat4 a3 = __builtin_nontemporal_load(nf4 + b + 3);
        nfloat4 m0 = __builtin_nontemporal_load(mem4 + b);
        nfloat4 m1 = __builtin_nontemporal_load(mem4 + b + 1);
        nfloat4 m2 = __builtin_nontemporal_load(mem4 + b + 2);
        nfloat4 m3 = __builtin_nontemporal_load(mem4 + b + 3);
        const nfloat4 s0 = a0 + m0, s1 = a1 + m1, s2 = a2 + m2, s3 = a3 + m3;
        __half2 h0[4], h1[4];
        h0[0] = __floats2half2_rn(s0.x, s0.y);
        h0[1] = __floats2half2_rn(s0.z, s0.w);
        h0[2] = __floats2half2_rn(s1.x, s1.y);
        h0[3] = __floats2half2_rn(s1.z, s1.w);
        h1[0] = __floats2half2_rn(s2.x, s2.y);
        h1[1] = __floats2half2_rn(s2.z, s2.w);
        h1[2] = __floats2half2_rn(s3.x, s3.y);
        h1[3] = __floats2half2_rn(s3.z, s3.w);
        sumh4[idx * 2]     = *(const nfloat4*)h0;   // normal store: keep in L3
        sumh4[idx * 2 + 1] = *(const nfloat4*)h1;
    }
    if (blockIdx.x == 0) {
        const int c = threadIdx.x;
        __shared__ float red[C_DIM];
        if (c < C_DIM) {
            float acc = 0.f;
            #pragma unroll 4
            for (int k = 0; k < C_DIM; ++k)
                acc += W_max[c * C_DIM + k] * W_score[k];
            combo[c] = acc;
            red[c] = b_max[c] * W_score[c];
        }
        __syncthreads();
        for (int off = 64; off > 0; off >>= 1) {
            if (c < off) red[c] += red[c + off];
            __syncthreads();
        }
        if (c == 0) combo[C_DIM] = red[0] + b_score[0];
    }
}

// ---------------------------------------------------------------------------
// Detector, TWO nodes per block (4096 blocks x 256 threads).
// q = tid&15 -> 16B chunk (8 channels), g = tid>>4 -> rows 4g..4g+3 per node.
// All 8 gather loads issued up-front; barriers amortized over 2 nodes;
// softmax/fitness phases: wave 0 <-> node 0, wave 1 <-> node 1.
// ---------------------------------------------------------------------------
__global__ __launch_bounds__(256)
void detector_half2_kernel(const float4* __restrict__ sum4,  // 8 halves each
                           const float* __restrict__ W_score,
                           const float* __restrict__ W_fit,
                           const float* __restrict__ b_fit,
                           const int* __restrict__ neighbors,
                           const float* __restrict__ combo,
                           float* __restrict__ out_cf,
                           float* __restrict__ out_score,
                           float* __restrict__ out_fit) {
    __shared__ float4 red4[2][256][2];   // 16 KB
    __shared__ float  chan[2][C_DIM];
    __shared__ float  s_raw[2][DEG];
    __shared__ float  sc[2][DEG];

    const int tid = threadIdx.x;
    const int n0  = blockIdx.x * 2;
    const int q   = tid & 15;
    const int g   = tid >> 4;

    int4 nb[2];
    nb[0] = ((const int4*)(neighbors + (long)n0 * DEG))[g];
    nb[1] = ((const int4*)(neighbors + (long)(n0 + 1) * DEG))[g];

    const float4 wsb0 = ((const float4*)(W_score + C_DIM))[2 * q];
    const float4 wsb1 = ((const float4*)(W_score + C_DIM))[2 * q + 1];

    // issue all 8 gathers back-to-back
    float4 vh[2][4];
    {
        const int ids0[4] = {nb[0].x, nb[0].y, nb[0].z, nb[0].w};
        const int ids1[4] = {nb[1].x, nb[1].y, nb[1].z, nb[1].w};
        #pragma unroll
        for (int i = 0; i < 4; ++i) vh[0][i] = sum4[(long)ids0[i] * 16 + q];
        #pragma unroll
        for (int i = 0; i < 4; ++i) vh[1][i] = sum4[(long)ids1[i] * 16 + q];
    }
    asm volatile("" ::: "memory");   // forbid remat of gather loads

    #pragma unroll
    for (int p = 0; p < 2; ++p) {
        float mx[8];
        #pragma unroll
        for (int k = 0; k < 8; ++k) mx[k] = -INFINITY;
        #pragma unroll
        for (int i = 0; i < 4; ++i) {
            const __half2* hp = (const __half2*)&vh[p][i];
            const float2 f0 = __half22float2(hp[0]);
            const float2 f1 = __half22float2(hp[1]);
            const float2 f2 = __half22float2(hp[2]);
            const float2 f3 = __half22float2(hp[3]);
            mx[0] = fmaxf(mx[0], f0.x); mx[1] = fmaxf(mx[1], f0.y);
            mx[2] = fmaxf(mx[2], f1.x); mx[3] = fmaxf(mx[3], f1.y);
            mx[4] = fmaxf(mx[4], f2.x); mx[5] = fmaxf(mx[5], f2.y);
            mx[6] = fmaxf(mx[6], f3.x); mx[7] = fmaxf(mx[7], f3.y);
            float pd = f0.x * wsb0.x + f0.y * wsb0.y + f1.x * wsb0.z + f1.y * wsb0.w
                     + f2.x * wsb1.x + f2.y * wsb1.y + f3.x * wsb1.z + f3.y * wsb1.w;
            pd += __shfl_xor(pd, 1);
            pd += __shfl_xor(pd, 2);
            pd += __shfl_xor(pd, 4);
            pd += __shfl_xor(pd, 8);
            if (q == 0) s_raw[p][g * 4 + i] = pd;
        }
        red4[p][tid][0] = make_float4(mx[0], mx[1], mx[2], mx[3]);
        red4[p][tid][1] = make_float4(mx[4], mx[5], mx[6], mx[7]);
    }
    __syncthreads();

    // per-channel max over the 16 row-groups; chan[p][c] = maxfeat*combo
    {
        const int p = tid >> 7, c = tid & 127;
        const int ch = c >> 3, k = c & 7;
        const float* rp = (const float*)red4[p];
        float f = rp[ch * 8 + k];
        #pragma unroll
        for (int g2 = 1; g2 < 16; ++g2)
            f = fmaxf(f, rp[(g2 * 16 + ch) * 8 + k]);
        chan[p][c] = f * combo[c];
    }
    __syncthreads();

    // center-half score + leaky-relu + softmax (wave p <-> node p)
    if (tid < 128) {
        const int p = tid >> 6, slot = tid & 63;
        float t1 = chan[p][slot] + chan[p][slot + 64];
        #pragma unroll
        for (int msk = 1; msk <= 32; msk <<= 1)
            t1 += __shfl_xor(t1, msk);
        t1 += combo[C_DIM];
        float s = t1 + s_raw[p][slot];
        s = (s >= 0.f) ? s : NEG_SLOPE * s;
        float m = s;
        #pragma unroll
        for (int msk = 1; msk <= 32; msk <<= 1)
            m = fmaxf(m, __shfl_xor(m, msk));
        const float ex = __expf(s - m);
        float d = ex;
        #pragma unroll
        for (int msk = 1; msk <= 32; msk <<= 1)
            d += __shfl_xor(d, msk);
        const float sv = ex / d;
        sc[p][slot] = sv;
        out_score[(long)(n0 + p) * DEG + slot] = sv;
    }
    __syncthreads();

    // score-weighted pooling from register tiles
    #pragma unroll
    for (int p = 0; p < 2; ++p) {
        float acc[8] = {0.f, 0.f, 0.f, 0.f, 0.f, 0.f, 0.f, 0.f};
        #pragma unroll
        for (int i = 0; i < 4; ++i) {
            const float w = sc[p][g * 4 + i];
            const __half2* hp = (const __half2*)&vh[p][i];
            const float2 f0 = __half22float2(hp[0]);
            const float2 f1 = __half22float2(hp[1]);
            const float2 f2 = __half22float2(hp[2]);
            const float2 f3 = __half22float2(hp[3]);
            acc[0] += f0.x * w; acc[1] += f0.y * w;
            acc[2] += f1.x * w; acc[3] += f1.y * w;
            acc[4] += f2.x * w; acc[5] += f2.y * w;
            acc[6] += f3.x * w; acc[7] += f3.y * w;
        }
        red4[p][tid][0] = make_float4(acc[0], acc[1], acc[2], acc[3]);
        red4[p][tid][1] = make_float4(acc[4], acc[5], acc[6], acc[7]);
    }
    __syncthreads();

    // channel sum + out_cf + fitness dot prep
    {
        const int p = tid >> 7, c = tid & 127;
        const int ch = c >> 3, k = c & 7;
        const float* rp = (const float*)red4[p];
        float f = 0.f;
        #pragma unroll
        for (int g2 = 0; g2 < 16; ++g2)
            f += rp[(g2 * 16 + ch) * 8 + k];
        out_cf[(long)(n0 + p) * C_DIM + c] = f;
        chan[p][c] = f * W_fit[c];
    }
    __syncthreads();

    if (tid < 128) {
        const int p = tid >> 6, slot = tid & 63;
        float t = chan[p][slot] + chan[p][slot + 64];
        #pragma unroll
        for (int msk = 1; msk <= 32; msk <<= 1)
            t += __shfl_xor(t, msk);
        if (slot == 0)
            out_fit[n0 + p] = 1.f / (1.f + __expf(-(t + b_fit[0])));
    }
}

// ---------------------------------------------------------------------------
// Fallback path (ws too small): fp32 two-array gather detector.
// ---------------------------------------------------------------------------
__global__ void precompute_kernel(const float* __restrict__ W_max,
                                  const float* __restrict__ b_max,
                                  const float* __restrict__ W_score,
                                  const float* __restrict__ b_score,
                                  float* __restrict__ combo) {
    const int c = threadIdx.x;
    float acc = 0.f;
    for (int k = 0; k < C_DIM; ++k)
        acc += W_max[c * C_DIM + k] * W_score[k];
    combo[c] = acc;
    __shared__ float red[C_DIM];
    red[c] = b_max[c] * W_score[c];
    __syncthreads();
    for (int off = 64; off > 0; off >>= 1) {
        if (c < off) red[c] += red[c + off];
        __syncthreads();
    }
    if (c == 0) combo[C_DIM] = red[0] + b_score[0];
}

__global__ __launch_bounds__(256)
void detector_f32_kernel(const float* __restrict__ nf,
                         const float* __restrict__ mem,
                         const float* __restrict__ W_score,
                         const float* __restrict__ W_fit,
                         const float* __restrict__ b_fit,
                         const int* __restrict__ neighbors,
                         const float* __restrict__ combo,
                         float* __restrict__ out_cf,
                         float* __restrict__ out_score,
                         float* __restrict__ out_fit) {
    __shared__ float4 red[256];
    __shared__ float  s_raw[DEG];
    __shared__ float  sc[DEG];
    __shared__ float  t1_sh;

    const int tid = threadIdx.x;
    const int n   = blockIdx.x;
    const int q   = tid & 31;
    const int g   = tid >> 5;

    const int4* nb4 = (const int4*)(neighbors + n * DEG + g * 8);
    const int4 nba = nb4[0];
    const int4 nbb = nb4[1];
    const int ids[8] = {nba.x, nba.y, nba.z, nba.w, nbb.x, nbb.y, nbb.z, nbb.w};
    const float4 wsb = ((const float4*)(W_score + C_DIM))[q];
    const float4* nf4  = (const float4*)nf;
    const float4* mem4 = (const float4*)mem;

    float4 v[8];
    float4 mx = make_float4(-INFINITY, -INFINITY, -INFINITY, -INFINITY);
    #pragma unroll
    for (int i = 0; i < 8; ++i) {
        const long node = ids[i];
        float4 vv = nf4[node * 32 + q];
        const float4 b = mem4[node * 32 + q];
        vv.x += b.x; vv.y += b.y; vv.z += b.z; vv.w += b.w;
        v[i] = vv;
        mx.x = fmaxf(mx.x, vv.x); mx.y = fmaxf(mx.y, vv.y);
        mx.z = fmaxf(mx.z, vv.z); mx.w = fmaxf(mx.w, vv.w);
        float p = vv.x * wsb.x + vv.y * wsb.y + vv.z * wsb.z + vv.w * wsb.w;
        p += __shfl_xor(p, 1); p += __shfl_xor(p, 2); p += __shfl_xor(p, 4);
        p += __shfl_xor(p, 8); p += __shfl_xor(p, 16);
        if (q == 0) s_raw[g * 8 + i] = p;
    }
    asm volatile("" ::: "memory");
    red[tid] = mx;
    __syncthreads();
    if (tid < 32) {
        float4 f = red[tid];
        #pragma unroll
        for (int r = 1; r < 8; ++r) {
            const float4 o = red[tid + 32 * r];
            f.x = fmaxf(f.x, o.x); f.y = fmaxf(f.y, o.y);
            f.z = fmaxf(f.z, o.z); f.w = fmaxf(f.w, o.w);
        }
        const float4 wc = ((const float4*)combo)[tid];
        float t1 = f.x * wc.x + f.y * wc.y + f.z * wc.z + f.w * wc.w;
        t1 += __shfl_xor(t1, 1); t1 += __shfl_xor(t1, 2); t1 += __shfl_xor(t1, 4);
        t1 += __shfl_xor(t1, 8); t1 += __shfl_xor(t1, 16);
        if (tid == 0) t1_sh = t1 + combo[C_DIM];
    }
    __syncthreads();
    if (tid < DEG) {
        float s = t1_sh + s_raw[tid];
        s = (s >= 0.f) ? s : NEG_SLOPE * s;
        float m = s;
        #pragma unroll
        for (int msk = 1; msk <= 32; msk <<= 1) m = fmaxf(m, __shfl_xor(m, msk));
        const float ex = __expf(s - m);
        float d = ex;
        #pragma unroll
        for (int msk = 1; msk <= 32; msk <<= 1) d += __shfl_xor(d, msk);
        const float sv = ex / d;
        sc[tid] = sv;
        out_score[n * DEG + tid] = sv;
    }
    __syncthreads();
    float4 acc = make_float4(0.f, 0.f, 0.f, 0.f);
    #pragma unroll
    for (int i = 0; i < 8; ++i) {
        const float w = sc[g * 8 + i];
        acc.x += v[i].x * w; acc.y += v[i].y * w;
        acc.z += v[i].z * w; acc.w += v[i].w * w;
    }
    red[tid] = acc;
    __syncthreads();
    if (tid < 32) {
        float4 f = red[tid];
        #pragma unroll
        for (int r = 1; r < 8; ++r) {
            const float4 o = red[tid + 32 * r];
            f.x += o.x; f.y += o.y; f.z += o.z; f.w += o.w;
        }
        ((float4*)(out_cf + (long)n * C_DIM))[tid] = f;
        const float4 wf = ((const float4*)W_fit)[tid];
        float fp = f.x * wf.x + f.y * wf.y + f.z * wf.z + f.w * wf.w;
        fp += __shfl_xor(fp, 1); fp += __shfl_xor(fp, 2); fp += __shfl_xor(fp, 4);
        fp += __shfl_xor(fp, 8); fp += __shfl_xor(fp, 16);
        if (tid == 0)
            out_fit[n] = 1.f / (1.f + __expf(-(fp + b_fit[0])));
    }
}

extern "C" void kernel_launch(void* const* d_in, const int* in_sizes, int n_in,
                              void* d_out, int out_size, void* d_ws, size_t ws_size,
                              hipStream_t stream) {
    const float* node_features = (const float*)d_in[0];
    const float* memory        = (const float*)d_in[1];
    const float* W_max         = (const float*)d_in[2];
    const float* b_max         = (const float*)d_in[3];
    const float* W_score       = (const float*)d_in[4];
    const float* b_score       = (const float*)d_in[5];
    const float* W_fit         = (const float*)d_in[6];
    const float* b_fit         = (const float*)d_in[7];
    const int*   neighbors     = (const int*)d_in[8];
    // d_in[9] = seg = repeat(arange(nodes), DEG)

    const long n_elem = (long)in_sizes[0];          // n_total * C
    const int  nodes  = in_sizes[8] / DEG;          // 8192
    const long n16    = (n_elem + 15) / 16;         // 16-element chunks

    float* combo = (float*)d_ws;                    // [129] (+pad to 512)
    __half* sumh = (__half*)(combo + 512);          // [n_elem] fp16, 16B-aligned
    const size_t need = 512 * sizeof(float) + (size_t)n_elem * sizeof(__half);

    float* out_cf    = (float*)d_out;                       // [nodes,128]
    float* out_score = out_cf + (long)nodes * C_DIM;        // [nodes,64]
    float* out_fit   = out_score + (long)nodes * DEG;       // [nodes]

    if (ws_size >= need && (n_elem % 16) == 0 && (nodes % 2) == 0) {
        const int blocks = (int)((n16 + 255) / 256);
        fuse_sum_half_kernel<<<blocks, 256, 0, stream>>>(
            (const nfloat4*)node_features, (const nfloat4*)memory,
            (nfloat4*)sumh, n16, W_max, b_max, W_score, b_score, combo);
        detector_half2_kernel<<<nodes / 2, 256, 0, stream>>>(
            (const float4*)sumh, W_score, W_fit, b_fit, neighbors, combo,
            out_cf, out_score, out_fit);
    } else {
        precompute_kernel<<<1, C_DIM, 0, stream>>>(W_max, b_max, W_score,
                                                   b_score, combo);
        detector_f32_kernel<<<nodes, 256, 0, stream>>>(
            node_features, memory, W_score, W_fit, b_fit, neighbors, combo,
            out_cf, out_score, out_fit);
    }
}

// Round 6
// 247.205 us; speedup vs baseline: 1.0956x; 1.0956x over previous
//
#include <hip/hip_runtime.h>
#include <hip/hip_fp16.h>
#include <math.h>

#define C_DIM 128
#define DEG 64
#define NEG_SLOPE 0.2f

typedef float nfloat4 __attribute__((ext_vector_type(4)));

// ---------------------------------------------------------------------------
// Streaming pre-pass: sum = (half)(nf + mem), fp16.
// One-shot launch; each thread handles 4 chunks at stride 256 within the
// block's 1024-chunk window -> every load/store instruction is fully
// lane-coalesced (16B loads, 8B stores), 8 independent NT loads in flight.
// Block 0 also computes combo[] (W_max @ W_score fold).
// ---------------------------------------------------------------------------
__global__ __launch_bounds__(256)
void fuse_sum_half_kernel(const nfloat4* __restrict__ nf4,
                          const nfloat4* __restrict__ mem4,
                          float2* __restrict__ outh,   // 4 halves per entry
                          long n4,
                          const float* __restrict__ W_max,
                          const float* __restrict__ b_max,
                          const float* __restrict__ W_score,
                          const float* __restrict__ b_score,
                          float* __restrict__ combo) {
    const long base = (long)blockIdx.x * 1024 + threadIdx.x;
    if (base + 768 < n4) {                       // fast path: no guards
        nfloat4 a0 = __builtin_nontemporal_load(nf4 + base);
        nfloat4 a1 = __builtin_nontemporal_load(nf4 + base + 256);
        nfloat4 a2 = __builtin_nontemporal_load(nf4 + base + 512);
        nfloat4 a3 = __builtin_nontemporal_load(nf4 + base + 768);
        nfloat4 m0 = __builtin_nontemporal_load(mem4 + base);
        nfloat4 m1 = __builtin_nontemporal_load(mem4 + base + 256);
        nfloat4 m2 = __builtin_nontemporal_load(mem4 + base + 512);
        nfloat4 m3 = __builtin_nontemporal_load(mem4 + base + 768);
        const nfloat4 s0 = a0 + m0, s1 = a1 + m1, s2 = a2 + m2, s3 = a3 + m3;
        __half2 p0[2], p1[2], p2[2], p3[2];
        p0[0] = __floats2half2_rn(s0.x, s0.y); p0[1] = __floats2half2_rn(s0.z, s0.w);
        p1[0] = __floats2half2_rn(s1.x, s1.y); p1[1] = __floats2half2_rn(s1.z, s1.w);
        p2[0] = __floats2half2_rn(s2.x, s2.y); p2[1] = __floats2half2_rn(s2.z, s2.w);
        p3[0] = __floats2half2_rn(s3.x, s3.y); p3[1] = __floats2half2_rn(s3.z, s3.w);
        outh[base]       = *(const float2*)p0;   // normal stores: keep in L3
        outh[base + 256] = *(const float2*)p1;
        outh[base + 512] = *(const float2*)p2;
        outh[base + 768] = *(const float2*)p3;
    } else {
        #pragma unroll
        for (int k = 0; k < 4; ++k) {
            const long i = base + k * 256;
            if (i < n4) {
                const nfloat4 a = __builtin_nontemporal_load(nf4 + i);
                const nfloat4 m = __builtin_nontemporal_load(mem4 + i);
                const nfloat4 s = a + m;
                __half2 p[2];
                p[0] = __floats2half2_rn(s.x, s.y);
                p[1] = __floats2half2_rn(s.z, s.w);
                outh[i] = *(const float2*)p;
            }
        }
    }
    if (blockIdx.x == 0) {
        const int c = threadIdx.x;
        __shared__ float red[C_DIM];
        if (c < C_DIM) {
            float acc = 0.f;
            #pragma unroll 4
            for (int k = 0; k < C_DIM; ++k)
                acc += W_max[c * C_DIM + k] * W_score[k];
            combo[c] = acc;
            red[c] = b_max[c] * W_score[c];
        }
        __syncthreads();
        for (int off = 64; off > 0; off >>= 1) {
            if (c < off) red[c] += red[c + off];
            __syncthreads();
        }
        if (c == 0) combo[C_DIM] = red[0] + b_score[0];
    }
}

// ---------------------------------------------------------------------------
// Detector, TWO nodes per block (4096 blocks x 256 threads).
// q = tid&15 -> 16B chunk (8 channels), g = tid>>4 -> rows 4g..4g+3 per node.
// All 8 gather loads issued up-front; barriers amortized over 2 nodes;
// softmax/fitness phases: wave 0 <-> node 0, wave 1 <-> node 1.
// ---------------------------------------------------------------------------
__global__ __launch_bounds__(256)
void detector_half2_kernel(const float4* __restrict__ sum4,  // 8 halves each
                           const float* __restrict__ W_score,
                           const float* __restrict__ W_fit,
                           const float* __restrict__ b_fit,
                           const int* __restrict__ neighbors,
                           const float* __restrict__ combo,
                           float* __restrict__ out_cf,
                           float* __restrict__ out_score,
                           float* __restrict__ out_fit) {
    __shared__ float4 red4[2][256][2];   // 16 KB
    __shared__ float  chan[2][C_DIM];
    __shared__ float  s_raw[2][DEG];
    __shared__ float  sc[2][DEG];

    const int tid = threadIdx.x;
    const int n0  = blockIdx.x * 2;
    const int q   = tid & 15;
    const int g   = tid >> 4;

    int4 nb[2];
    nb[0] = ((const int4*)(neighbors + (long)n0 * DEG))[g];
    nb[1] = ((const int4*)(neighbors + (long)(n0 + 1) * DEG))[g];

    const float4 wsb0 = ((const float4*)(W_score + C_DIM))[2 * q];
    const float4 wsb1 = ((const float4*)(W_score + C_DIM))[2 * q + 1];

    // issue all 8 gathers back-to-back
    float4 vh[2][4];
    {
        const int ids0[4] = {nb[0].x, nb[0].y, nb[0].z, nb[0].w};
        const int ids1[4] = {nb[1].x, nb[1].y, nb[1].z, nb[1].w};
        #pragma unroll
        for (int i = 0; i < 4; ++i) vh[0][i] = sum4[(long)ids0[i] * 16 + q];
        #pragma unroll
        for (int i = 0; i < 4; ++i) vh[1][i] = sum4[(long)ids1[i] * 16 + q];
    }
    asm volatile("" ::: "memory");   // forbid remat of gather loads

    #pragma unroll
    for (int p = 0; p < 2; ++p) {
        float mx[8];
        #pragma unroll
        for (int k = 0; k < 8; ++k) mx[k] = -INFINITY;
        #pragma unroll
        for (int i = 0; i < 4; ++i) {
            const __half2* hp = (const __half2*)&vh[p][i];
            const float2 f0 = __half22float2(hp[0]);
            const float2 f1 = __half22float2(hp[1]);
            const float2 f2 = __half22float2(hp[2]);
            const float2 f3 = __half22float2(hp[3]);
            mx[0] = fmaxf(mx[0], f0.x); mx[1] = fmaxf(mx[1], f0.y);
            mx[2] = fmaxf(mx[2], f1.x); mx[3] = fmaxf(mx[3], f1.y);
            mx[4] = fmaxf(mx[4], f2.x); mx[5] = fmaxf(mx[5], f2.y);
            mx[6] = fmaxf(mx[6], f3.x); mx[7] = fmaxf(mx[7], f3.y);
            float pd = f0.x * wsb0.x + f0.y * wsb0.y + f1.x * wsb0.z + f1.y * wsb0.w
                     + f2.x * wsb1.x + f2.y * wsb1.y + f3.x * wsb1.z + f3.y * wsb1.w;
            pd += __shfl_xor(pd, 1);
            pd += __shfl_xor(pd, 2);
            pd += __shfl_xor(pd, 4);
            pd += __shfl_xor(pd, 8);
            if (q == 0) s_raw[p][g * 4 + i] = pd;
        }
        red4[p][tid][0] = make_float4(mx[0], mx[1], mx[2], mx[3]);
        red4[p][tid][1] = make_float4(mx[4], mx[5], mx[6], mx[7]);
    }
    __syncthreads();

    // per-channel max over the 16 row-groups; chan[p][c] = maxfeat*combo
    {
        const int p = tid >> 7, c = tid & 127;
        const int ch = c >> 3, k = c & 7;
        const float* rp = (const float*)red4[p];
        float f = rp[ch * 8 + k];
        #pragma unroll
        for (int g2 = 1; g2 < 16; ++g2)
            f = fmaxf(f, rp[(g2 * 16 + ch) * 8 + k]);
        chan[p][c] = f * combo[c];
    }
    __syncthreads();

    // center-half score + leaky-relu + softmax (wave p <-> node p)
    if (tid < 128) {
        const int p = tid >> 6, slot = tid & 63;
        float t1 = chan[p][slot] + chan[p][slot + 64];
        #pragma unroll
        for (int msk = 1; msk <= 32; msk <<= 1)
            t1 += __shfl_xor(t1, msk);
        t1 += combo[C_DIM];
        float s = t1 + s_raw[p][slot];
        s = (s >= 0.f) ? s : NEG_SLOPE * s;
        float m = s;
        #pragma unroll
        for (int msk = 1; msk <= 32; msk <<= 1)
            m = fmaxf(m, __shfl_xor(m, msk));
        const float ex = __expf(s - m);
        float d = ex;
        #pragma unroll
        for (int msk = 1; msk <= 32; msk <<= 1)
            d += __shfl_xor(d, msk);
        const float sv = ex / d;
        sc[p][slot] = sv;
        out_score[(long)(n0 + p) * DEG + slot] = sv;
    }
    __syncthreads();

    // score-weighted pooling from register tiles
    #pragma unroll
    for (int p = 0; p < 2; ++p) {
        float acc[8] = {0.f, 0.f, 0.f, 0.f, 0.f, 0.f, 0.f, 0.f};
        #pragma unroll
        for (int i = 0; i < 4; ++i) {
            const float w = sc[p][g * 4 + i];
            const __half2* hp = (const __half2*)&vh[p][i];
            const float2 f0 = __half22float2(hp[0]);
            const float2 f1 = __half22float2(hp[1]);
            const float2 f2 = __half22float2(hp[2]);
            const float2 f3 = __half22float2(hp[3]);
            acc[0] += f0.x * w; acc[1] += f0.y * w;
            acc[2] += f1.x * w; acc[3] += f1.y * w;
            acc[4] += f2.x * w; acc[5] += f2.y * w;
            acc[6] += f3.x * w; acc[7] += f3.y * w;
        }
        red4[p][tid][0] = make_float4(acc[0], acc[1], acc[2], acc[3]);
        red4[p][tid][1] = make_float4(acc[4], acc[5], acc[6], acc[7]);
    }
    __syncthreads();

    // channel sum + out_cf + fitness dot prep
    {
        const int p = tid >> 7, c = tid & 127;
        const int ch = c >> 3, k = c & 7;
        const float* rp = (const float*)red4[p];
        float f = 0.f;
        #pragma unroll
        for (int g2 = 0; g2 < 16; ++g2)
            f += rp[(g2 * 16 + ch) * 8 + k];
        out_cf[(long)(n0 + p) * C_DIM + c] = f;
        chan[p][c] = f * W_fit[c];
    }
    __syncthreads();

    if (tid < 128) {
        const int p = tid >> 6, slot = tid & 63;
        float t = chan[p][slot] + chan[p][slot + 64];
        #pragma unroll
        for (int msk = 1; msk <= 32; msk <<= 1)
            t += __shfl_xor(t, msk);
        if (slot == 0)
            out_fit[n0 + p] = 1.f / (1.f + __expf(-(t + b_fit[0])));
    }
}

// ---------------------------------------------------------------------------
// Fallback path (ws too small): fp32 two-array gather detector.
// ---------------------------------------------------------------------------
__global__ void precompute_kernel(const float* __restrict__ W_max,
                                  const float* __restrict__ b_max,
                                  const float* __restrict__ W_score,
                                  const float* __restrict__ b_score,
                                  float* __restrict__ combo) {
    const int c = threadIdx.x;
    float acc = 0.f;
    for (int k = 0; k < C_DIM; ++k)
        acc += W_max[c * C_DIM + k] * W_score[k];
    combo[c] = acc;
    __shared__ float red[C_DIM];
    red[c] = b_max[c] * W_score[c];
    __syncthreads();
    for (int off = 64; off > 0; off >>= 1) {
        if (c < off) red[c] += red[c + off];
        __syncthreads();
    }
    if (c == 0) combo[C_DIM] = red[0] + b_score[0];
}

__global__ __launch_bounds__(256)
void detector_f32_kernel(const float* __restrict__ nf,
                         const float* __restrict__ mem,
                         const float* __restrict__ W_score,
                         const float* __restrict__ W_fit,
                         const float* __restrict__ b_fit,
                         const int* __restrict__ neighbors,
                         const float* __restrict__ combo,
                         float* __restrict__ out_cf,
                         float* __restrict__ out_score,
                         float* __restrict__ out_fit) {
    __shared__ float4 red[256];
    __shared__ float  s_raw[DEG];
    __shared__ float  sc[DEG];
    __shared__ float  t1_sh;

    const int tid = threadIdx.x;
    const int n   = blockIdx.x;
    const int q   = tid & 31;
    const int g   = tid >> 5;

    const int4* nb4 = (const int4*)(neighbors + n * DEG + g * 8);
    const int4 nba = nb4[0];
    const int4 nbb = nb4[1];
    const int ids[8] = {nba.x, nba.y, nba.z, nba.w, nbb.x, nbb.y, nbb.z, nbb.w};
    const float4 wsb = ((const float4*)(W_score + C_DIM))[q];
    const float4* nf4  = (const float4*)nf;
    const float4* mem4 = (const float4*)mem;

    float4 v[8];
    float4 mx = make_float4(-INFINITY, -INFINITY, -INFINITY, -INFINITY);
    #pragma unroll
    for (int i = 0; i < 8; ++i) {
        const long node = ids[i];
        float4 vv = nf4[node * 32 + q];
        const float4 b = mem4[node * 32 + q];
        vv.x += b.x; vv.y += b.y; vv.z += b.z; vv.w += b.w;
        v[i] = vv;
        mx.x = fmaxf(mx.x, vv.x); mx.y = fmaxf(mx.y, vv.y);
        mx.z = fmaxf(mx.z, vv.z); mx.w = fmaxf(mx.w, vv.w);
        float p = vv.x * wsb.x + vv.y * wsb.y + vv.z * wsb.z + vv.w * wsb.w;
        p += __shfl_xor(p, 1); p += __shfl_xor(p, 2); p += __shfl_xor(p, 4);
        p += __shfl_xor(p, 8); p += __shfl_xor(p, 16);
        if (q == 0) s_raw[g * 8 + i] = p;
    }
    asm volatile("" ::: "memory");
    red[tid] = mx;
    __syncthreads();
    if (tid < 32) {
        float4 f = red[tid];
        #pragma unroll
        for (int r = 1; r < 8; ++r) {
            const float4 o = red[tid + 32 * r];
            f.x = fmaxf(f.x, o.x); f.y = fmaxf(f.y, o.y);
            f.z = fmaxf(f.z, o.z); f.w = fmaxf(f.w, o.w);
        }
        const float4 wc = ((const float4*)combo)[tid];
        float t1 = f.x * wc.x + f.y * wc.y + f.z * wc.z + f.w * wc.w;
        t1 += __shfl_xor(t1, 1); t1 += __shfl_xor(t1, 2); t1 += __shfl_xor(t1, 4);
        t1 += __shfl_xor(t1, 8); t1 += __shfl_xor(t1, 16);
        if (tid == 0) t1_sh = t1 + combo[C_DIM];
    }
    __syncthreads();
    if (tid < DEG) {
        float s = t1_sh + s_raw[tid];
        s = (s >= 0.f) ? s : NEG_SLOPE * s;
        float m = s;
        #pragma unroll
        for (int msk = 1; msk <= 32; msk <<= 1) m = fmaxf(m, __shfl_xor(m, msk));
        const float ex = __expf(s - m);
        float d = ex;
        #pragma unroll
        for (int msk = 1; msk <= 32; msk <<= 1) d += __shfl_xor(d, msk);
        const float sv = ex / d;
        sc[tid] = sv;
        out_score[n * DEG + tid] = sv;
    }
    __syncthreads();
    float4 acc = make_float4(0.f, 0.f, 0.f, 0.f);
    #pragma unroll
    for (int i = 0; i < 8; ++i) {
        const float w = sc[g * 8 + i];
        acc.x += v[i].x * w; acc.y += v[i].y * w;
        acc.z += v[i].z * w; acc.w += v[i].w * w;
    }
    red[tid] = acc;
    __syncthreads();
    if (tid < 32) {
        float4 f = red[tid];
        #pragma unroll
        for (int r = 1; r < 8; ++r) {
            const float4 o = red[tid + 32 * r];
            f.x += o.x; f.y += o.y; f.z += o.z; f.w += o.w;
        }
        ((float4*)(out_cf + (long)n * C_DIM))[tid] = f;
        const float4 wf = ((const float4*)W_fit)[tid];
        float fp = f.x * wf.x + f.y * wf.y + f.z * wf.z + f.w * wf.w;
        fp += __shfl_xor(fp, 1); fp += __shfl_xor(fp, 2); fp += __shfl_xor(fp, 4);
        fp += __shfl_xor(fp, 8); fp += __shfl_xor(fp, 16);
        if (tid == 0)
            out_fit[n] = 1.f / (1.f + __expf(-(fp + b_fit[0])));
    }
}

extern "C" void kernel_launch(void* const* d_in, const int* in_sizes, int n_in,
                              void* d_out, int out_size, void* d_ws, size_t ws_size,
                              hipStream_t stream) {
    const float* node_features = (const float*)d_in[0];
    const float* memory        = (const float*)d_in[1];
    const float* W_max         = (const float*)d_in[2];
    const float* b_max         = (const float*)d_in[3];
    const float* W_score       = (const float*)d_in[4];
    const float* b_score       = (const float*)d_in[5];
    const float* W_fit         = (const float*)d_in[6];
    const float* b_fit         = (const float*)d_in[7];
    const int*   neighbors     = (const int*)d_in[8];
    // d_in[9] = seg = repeat(arange(nodes), DEG)

    const long n_elem = (long)in_sizes[0];          // n_total * C
    const int  nodes  = in_sizes[8] / DEG;          // 8192
    const long n4     = n_elem / 4;                 // float4 chunks

    float* combo = (float*)d_ws;                    // [129] (+pad to 512)
    __half* sumh = (__half*)(combo + 512);          // [n_elem] fp16, 16B-aligned
    const size_t need = 512 * sizeof(float) + (size_t)n_elem * sizeof(__half);

    float* out_cf    = (float*)d_out;                       // [nodes,128]
    float* out_score = out_cf + (long)nodes * C_DIM;        // [nodes,64]
    float* out_fit   = out_score + (long)nodes * DEG;       // [nodes]

    if (ws_size >= need && (n_elem % 4) == 0 && (nodes % 2) == 0) {
        const int blocks = (int)((n4 + 1023) / 1024);
        fuse_sum_half_kernel<<<blocks, 256, 0, stream>>>(
            (const nfloat4*)node_features, (const nfloat4*)memory,
            (float2*)sumh, n4, W_max, b_max, W_score, b_score, combo);
        detector_half2_kernel<<<nodes / 2, 256, 0, stream>>>(
            (const float4*)sumh, W_score, W_fit, b_fit, neighbors, combo,
            out_cf, out_score, out_fit);
    } else {
        precompute_kernel<<<1, C_DIM, 0, stream>>>(W_max, b_max, W_score,
                                                   b_score, combo);
        detector_f32_kernel<<<nodes, 256, 0, stream>>>(
            node_features, memory, W_score, W_fit, b_fit, neighbors, combo,
            out_cf, out_score, out_fit);
    }
}